// Round 4
// baseline (171.681 us; speedup 1.0000x reference)
//
#include <hip/hip_runtime.h>
#include <math.h>

// ForceMatchingLoss — R4: split into two streaming kernels.
// A (scores_kernel, 1 blk/batch): scores+softmax+w+cg-probs -> ws. K read ONCE from HBM.
// B (jac_kernel, 2 blk/batch, XCD-pair-swizzled): jacobian GEMM + out/kbar + cg + loss,
//    K re-read served by L3 (A streamed it), V cold.
// agg_jac = SCALE * ( V^T diag(w) K - Out^T Kbar ), w_s = sum_q p_qs.

namespace {
constexpr int Bn = 256, Qn = 16, Sn = 512, Mn = 8, Dn = 128;
constexpr int NT = 512;
constexpr float SCALE = 0.08838834764831845f;  // 1/sqrt(128)
constexpr float CLIPV = 50.0f;

// ---- ws layout ----
// P    bf16 [256][16][512]  @ byte 0        (4,194,304)
// W    f32  [256][512]      @ byte 4194304  (524,288)
// PCG  bf16 [256][16][8]    @ byte 4718592  (65,536)
// WC   f32  [256][8]        @ byte 4784128  (8,192)
// PART f32  [256][4]        @ byte 4792320  (4,096)
constexpr int W_OFF_F = 1048576;
constexpr int PCG_OFF_B = 4718592;
constexpr int WC_OFF_F = 1196032;
constexpr int PART_OFF_F = 1198080;

typedef __attribute__((ext_vector_type(8))) short bf16x8;
typedef __attribute__((ext_vector_type(4))) float f32x4;
#define MFMA16(a, b, c) __builtin_amdgcn_mfma_f32_16x16x32_bf16((a), (b), (c), 0, 0, 0)

__device__ inline unsigned int pack2t(float a, float b) {  // truncating pack, 1 v_perm
  return __builtin_amdgcn_perm(__builtin_bit_cast(unsigned int, b),
                               __builtin_bit_cast(unsigned int, a), 0x07060302u);
}
__device__ inline unsigned short f2bf(float x) {  // RNE
  unsigned int u = __builtin_bit_cast(unsigned int, x);
  u += 0x7fffu + ((u >> 16) & 1u);
  return (unsigned short)(u >> 16);
}
__device__ inline float bf2f(unsigned short h) {
  unsigned int u = ((unsigned int)h) << 16;
  return __builtin_bit_cast(float, u);
}
union Frag {
  bf16x8 v;
  unsigned int u[4];
  unsigned short h[8];
};

// =====================  Kernel A  =====================
// LDS: QS bf16[16][136] @0 (4352) | PB ushort[16][520] @4352 (16640)
//      RDM f32[16][8] @20992 | RDS f32[16][8] @21504 | CGS f32[16][8] @22016
//      CGP ushort[16][8] @22528 -> 22784
constexpr int A_QS = 0, A_PB = 4352, A_RDM = 20992, A_RDS = 21504,
              A_CGS = 22016, A_CGP = 22528, A_LDSZ = 22784;

__global__ __launch_bounds__(NT) void scores_kernel(
    const float* __restrict__ Qg, const float* __restrict__ Kg,
    const float* __restrict__ Kcg, float* __restrict__ ws) {
  __shared__ __align__(16) char L[A_LDSZ];
  const int b = blockIdx.x, t = threadIdx.x;
  const int lane = t & 63, wv = t >> 6, quad = lane >> 4, l16 = lane & 15;
  const float* Qb = Qg + (size_t)b * Qn * Dn;
  const float* Kb = Kg + (size_t)b * Sn * Dn;
  const float* Kc = Kcg + (size_t)b * Mn * Dn;

  if (t == 0)  // zero this batch's loss partials (B runs strictly after A)
    *(float4*)(ws + PART_OFF_F + b * 4) = make_float4(0.f, 0.f, 0.f, 0.f);

  // Q (pre-scaled) -> QS bf16
  {
    int row = t >> 5, c4 = t & 31;
    float4 qv = ((const float4*)Qb)[t];
    unsigned int p0 = pack2t(qv.x * SCALE, qv.y * SCALE);
    unsigned int p1 = pack2t(qv.z * SCALE, qv.w * SCALE);
    *(unsigned long long*)(L + A_QS + row * 272 + c4 * 8) =
        (unsigned long long)p0 | ((unsigned long long)p1 << 32);
  }
  __syncthreads();

  // dense scores: wave wv owns s-range [64wv, 64wv+64); acc[j] tile j
  bf16x8 aq[4];
#pragma unroll
  for (int kk = 0; kk < 4; ++kk)
    aq[kk] = *(const bf16x8*)(L + A_QS + l16 * 272 + kk * 64 + quad * 16);
  f32x4 acc[4];
#pragma unroll
  for (int j = 0; j < 4; ++j) {
    const float* kp = Kb + (size_t)(64 * wv + 16 * j + l16) * Dn + quad * 8;
    f32x4 a = {0.f, 0.f, 0.f, 0.f};
#pragma unroll
    for (int kk = 0; kk < 4; ++kk) {
      float4 lo = *(const float4*)(kp + kk * 32);
      float4 hi = *(const float4*)(kp + kk * 32 + 4);
      Frag f;
      f.u[0] = pack2t(lo.x, lo.y);
      f.u[1] = pack2t(lo.z, lo.w);
      f.u[2] = pack2t(hi.x, hi.y);
      f.u[3] = pack2t(hi.z, hi.w);
      a = MFMA16(aq[kk], f.v, a);
    }
    acc[j] = a;
  }
  // row max: lane holds q=quad*4+r, s=64wv+16j+l16
  {
    float pm[4];
#pragma unroll
    for (int r = 0; r < 4; ++r)
      pm[r] = fmaxf(fmaxf(acc[0][r], acc[1][r]), fmaxf(acc[2][r], acc[3][r]));
#pragma unroll
    for (int o = 1; o < 16; o <<= 1)
#pragma unroll
      for (int r = 0; r < 4; ++r) pm[r] = fmaxf(pm[r], __shfl_xor(pm[r], o));
    if (l16 == 0)
#pragma unroll
      for (int r = 0; r < 4; ++r) *(float*)(L + A_RDM + (quad * 4 + r) * 32 + wv * 4) = pm[r];
  }
  __syncthreads();
  float gm[4];
#pragma unroll
  for (int r = 0; r < 4; ++r) {
    const float* p = (const float*)(L + A_RDM + (quad * 4 + r) * 32);
    float m = p[0];
#pragma unroll
    for (int w = 1; w < 8; ++w) m = fmaxf(m, p[w]);
    gm[r] = m;
  }
  float e[4][4];
  {
    float ps[4] = {0.f, 0.f, 0.f, 0.f};
#pragma unroll
    for (int j = 0; j < 4; ++j)
#pragma unroll
      for (int r = 0; r < 4; ++r) {
        e[j][r] = __expf(acc[j][r] - gm[r]);
        ps[r] += e[j][r];
      }
#pragma unroll
    for (int o = 1; o < 16; o <<= 1)
#pragma unroll
      for (int r = 0; r < 4; ++r) ps[r] += __shfl_xor(ps[r], o);
    if (l16 == 0)
#pragma unroll
      for (int r = 0; r < 4; ++r) *(float*)(L + A_RDS + (quad * 4 + r) * 32 + wv * 4) = ps[r];
  }
  __syncthreads();
  float inv[4];
#pragma unroll
  for (int r = 0; r < 4; ++r) {
    const float* p = (const float*)(L + A_RDS + (quad * 4 + r) * 32);
    float s = 0.f;
#pragma unroll
    for (int w = 0; w < 8; ++w) s += p[w];
    inv[r] = 1.f / s;
  }
  // probs bf16 -> PB
#pragma unroll
  for (int j = 0; j < 4; ++j)
#pragma unroll
    for (int r = 0; r < 4; ++r)
      *(unsigned short*)(L + A_PB + (quad * 4 + r) * 1040 + (64 * wv + 16 * j + l16) * 2) =
          f2bf(e[j][r] * inv[r]);
  __syncthreads();
  // w_s and P copy to global
  {
    float wsum = 0.f;
#pragma unroll
    for (int q = 0; q < Qn; ++q)
      wsum += bf2f(*(const unsigned short*)(L + A_PB + q * 1040 + t * 2));
    ws[W_OFF_F + b * 512 + t] = wsum;
  }
#pragma unroll
  for (int i = 0; i < 2; ++i) {
    int idx = t + i * 512, q = idx >> 6, c = idx & 63;
    *(uint4*)((char*)ws + (size_t)b * 16384 + q * 1024 + c * 16) =
        *(const uint4*)(L + A_PB + q * 1040 + c * 16);
  }
  // cg scores (wave 0)
  if (wv == 0) {
    const float* kp = Kc + (size_t)(l16 & 7) * Dn + quad * 8;
    f32x4 a = {0.f, 0.f, 0.f, 0.f};
#pragma unroll
    for (int kk = 0; kk < 4; ++kk) {
      float4 lo = *(const float4*)(kp + kk * 32);
      float4 hi = *(const float4*)(kp + kk * 32 + 4);
      Frag f;
      f.u[0] = pack2t(lo.x, lo.y);
      f.u[1] = pack2t(lo.z, lo.w);
      f.u[2] = pack2t(hi.x, hi.y);
      f.u[3] = pack2t(hi.z, hi.w);
      a = MFMA16(aq[kk], f.v, a);
    }
    if (l16 < 8)
#pragma unroll
      for (int r = 0; r < 4; ++r)
        *(float*)(L + A_CGS + (quad * 4 + r) * 32 + l16 * 4) = a[r];
  }
  __syncthreads();
  if (t < 16) {  // cg softmax row t -> global PCG + LDS CGP
    float xs[8];
    float m = -1e30f;
#pragma unroll
    for (int s = 0; s < 8; ++s) {
      xs[s] = *(const float*)(L + A_CGS + t * 32 + s * 4);
      m = fmaxf(m, xs[s]);
    }
    float ssum = 0.f;
#pragma unroll
    for (int s = 0; s < 8; ++s) {
      xs[s] = __expf(xs[s] - m);
      ssum += xs[s];
    }
    float iv = 1.f / ssum;
    uint4 pk = make_uint4(pack2t(xs[0] * iv, xs[1] * iv), pack2t(xs[2] * iv, xs[3] * iv),
                          pack2t(xs[4] * iv, xs[5] * iv), pack2t(xs[6] * iv, xs[7] * iv));
    *(uint4*)(L + A_CGP + t * 16) = pk;
    *(uint4*)((char*)ws + PCG_OFF_B + b * 256 + t * 16) = pk;
  }
  __syncthreads();
  if (t < 8) {
    float s = 0.f;
#pragma unroll
    for (int q = 0; q < Qn; ++q)
      s += bf2f(*(const unsigned short*)(L + A_CGP + q * 16 + t * 2));
    ws[WC_OFF_F + b * 8 + t] = s;
  }
}

// =====================  Kernel B  =====================
// LDS: PB ushort[16][520] @0 (16640) | WOFF f32[512] @16640 (2048)
//      arena @18688: KT bf16[128][72] (18432) | VT bf16[64][72] @37120 (9216)
//      VTW bf16[64][72] @46336 (9216) | PCG @55552 (1280) | WC @56832 (32)
//      RED @56864 (128) -> 56992
constexpr int B_PB = 0, B_WOFF = 16640, B_KT = 18688, B_VT = 37120, B_VTW = 46336,
              B_PCG = 55552, B_WC = 56832, B_RED = 56864, B_LDSZ = 56992;

__global__ __launch_bounds__(NT, 4) void jac_kernel(
    const float* __restrict__ Kg, const float* __restrict__ Vg,
    const float* __restrict__ Kcg, const float* __restrict__ Vcg,
    float* __restrict__ ws) {
  __shared__ __align__(16) char L[B_LDSZ];
  const int g = blockIdx.x;
  const int h = (g >> 3) & 1;                 // pair-partner differs by 8 -> same XCD
  const int b = (g & 7) | ((g >> 4) << 3);
  const int t = threadIdx.x, lane = t & 63, wv = t >> 6;
  const int quad = lane >> 4, l16 = lane & 15;

  const float* Kb = Kg + (size_t)b * Sn * Dn;
  const float* Vb = Vg + (size_t)b * Sn * Dn;
  const float* Kc = Kcg + (size_t)b * Mn * Dn;
  const float* Vc = Vcg + (size_t)b * Mn * Dn;

  // staging roles: thread owns 8 consecutive s for one dim
  const int dK = t & 127, gK = t >> 7;
  const int dV = t & 63, gV = t >> 6;
  float kpf[2][8], vpf[8];

  auto load_tiles = [&](int st) {
#pragma unroll
    for (int o = 0; o < 2; ++o) {
      int s0 = st * 64 + (gK + 4 * o) * 8;
#pragma unroll
      for (int i = 0; i < 8; ++i) kpf[o][i] = Kb[(size_t)(s0 + i) * Dn + dK];
    }
    int s1 = st * 64 + gV * 8;
#pragma unroll
    for (int i = 0; i < 8; ++i) vpf[i] = Vb[(size_t)(s1 + i) * Dn + h * 64 + dV];
  };
  auto store_tiles = [&](int st) {
#pragma unroll
    for (int o = 0; o < 2; ++o) {
      unsigned int u0 = pack2t(kpf[o][0], kpf[o][1]), u1 = pack2t(kpf[o][2], kpf[o][3]);
      unsigned int u2 = pack2t(kpf[o][4], kpf[o][5]), u3 = pack2t(kpf[o][6], kpf[o][7]);
      *(uint4*)(L + B_KT + dK * 144 + (gK + 4 * o) * 16) = make_uint4(u0, u1, u2, u3);
    }
    int s1 = st * 64 + gV * 8;
    float w8[8];
#pragma unroll
    for (int i = 0; i < 8; ++i) w8[i] = *(const float*)(L + B_WOFF + (s1 + i) * 4);
    *(uint4*)(L + B_VT + dV * 144 + gV * 16) =
        make_uint4(pack2t(vpf[0], vpf[1]), pack2t(vpf[2], vpf[3]),
                   pack2t(vpf[4], vpf[5]), pack2t(vpf[6], vpf[7]));
    *(uint4*)(L + B_VTW + dV * 144 + gV * 16) =
        make_uint4(pack2t(w8[0] * vpf[0], w8[1] * vpf[1]), pack2t(w8[2] * vpf[2], w8[3] * vpf[3]),
                   pack2t(w8[4] * vpf[4], w8[5] * vpf[5]), pack2t(w8[6] * vpf[6], w8[7] * vpf[7]));
  };

  // preload P, w, cg-probs, wc
#pragma unroll
  for (int i = 0; i < 2; ++i) {
    int idx = t + i * 512, q = idx >> 6, c = idx & 63;
    *(uint4*)(L + B_PB + q * 1040 + c * 16) =
        *(const uint4*)((const char*)ws + (size_t)b * 16384 + q * 1024 + c * 16);
  }
  *(float*)(L + B_WOFF + t * 4) = ws[W_OFF_F + b * 512 + t];
  if (t < 16) {
    uint4 pv = *(const uint4*)((const char*)ws + PCG_OFF_B + b * 256 + t * 16);
    *(uint4*)(L + B_PCG + t * 80) = pv;
    *(uint4*)(L + B_PCG + t * 80 + 16) = make_uint4(0, 0, 0, 0);
    *(uint4*)(L + B_PCG + t * 80 + 32) = make_uint4(0, 0, 0, 0);
    *(uint4*)(L + B_PCG + t * 80 + 48) = make_uint4(0, 0, 0, 0);
  }
  if (t < 8) *(float*)(L + B_WC + t * 4) = ws[WC_OFF_F + b * 8 + t];
  load_tiles(0);
  __syncthreads();

  // main loop
  const int rp = wv & 1, ch = wv >> 1;
  f32x4 C00 = {0.f,0.f,0.f,0.f}, C01 = {0.f,0.f,0.f,0.f};
  f32x4 C10 = {0.f,0.f,0.f,0.f}, C11 = {0.f,0.f,0.f,0.f};
  f32x4 outacc = {0.f,0.f,0.f,0.f}, kbacc = {0.f,0.f,0.f,0.f};

  auto ckstep = [&](int colByte, f32x4& c00, f32x4& c01, f32x4& c10, f32x4& c11) {
    bf16x8 A0 = *(const bf16x8*)(L + B_VTW + (rp * 32 + l16) * 144 + colByte + quad * 16);
    bf16x8 A1 = *(const bf16x8*)(L + B_VTW + (rp * 32 + 16 + l16) * 144 + colByte + quad * 16);
    bf16x8 B0 = *(const bf16x8*)(L + B_KT + (ch * 32 + l16) * 144 + colByte + quad * 16);
    bf16x8 B1 = *(const bf16x8*)(L + B_KT + (ch * 32 + 16 + l16) * 144 + colByte + quad * 16);
    c00 = MFMA16(A0, B0, c00);
    c01 = MFMA16(A0, B1, c01);
    c10 = MFMA16(A1, B0, c10);
    c11 = MFMA16(A1, B1, c11);
  };

  for (int st = 0; st < 8; ++st) {
    if (st) __syncthreads();
    store_tiles(st);
    __syncthreads();
    if (st < 7) load_tiles(st + 1);
#pragma unroll
    for (int z = 0; z < 2; ++z) {
      int colByte = z * 64;
      bf16x8 pA = *(const bf16x8*)(L + B_PB + l16 * 1040 + st * 128 + z * 64 + quad * 16);
      bf16x8 bK = *(const bf16x8*)(L + B_KT + (wv * 16 + l16) * 144 + colByte + quad * 16);
      kbacc = MFMA16(pA, bK, kbacc);
      if (wv < 4) {
        bf16x8 bV = *(const bf16x8*)(L + B_VT + (wv * 16 + l16) * 144 + colByte + quad * 16);
        outacc = MFMA16(pA, bV, outacc);
      }
      ckstep(colByte, C00, C01, C10, C11);
    }
  }
  __syncthreads();

  // pseudo k-step: C -= Out^T · Kbar
  if (wv < 4) {
#pragma unroll
    for (int r = 0; r < 4; ++r)
      *(unsigned short*)(L + B_VTW + (wv * 16 + l16) * 144 + (quad * 4 + r) * 2) = f2bf(-outacc[r]);
  }
#pragma unroll
  for (int r = 0; r < 4; ++r)
    *(unsigned short*)(L + B_KT + (wv * 16 + l16) * 144 + (quad * 4 + r) * 2) = f2bf(kbacc[r]);
  if (t < 256) {
    *(uint4*)(L + B_KT + (t >> 1) * 144 + 32 + (t & 1) * 16) = make_uint4(0, 0, 0, 0);
  } else if (t < 384) {
    int i = t - 256;
    *(uint4*)(L + B_VTW + (i >> 1) * 144 + 32 + (i & 1) * 16) = make_uint4(0, 0, 0, 0);
  }
  __syncthreads();
  ckstep(0, C00, C01, C10, C11);
#pragma unroll
  for (int r = 0; r < 4; ++r) {
    C00[r] = fminf(fmaxf(SCALE * C00[r], -CLIPV), CLIPV);
    C01[r] = fminf(fmaxf(SCALE * C01[r], -CLIPV), CLIPV);
    C10[r] = fminf(fmaxf(SCALE * C10[r], -CLIPV), CLIPV);
    C11[r] = fminf(fmaxf(SCALE * C11[r], -CLIPV), CLIPV);
  }
  __syncthreads();  // arena free for CG

  // stage CG transposed (cols 8..31 zero)
  if (t < 128) {
    float kv[8];
#pragma unroll
    for (int i = 0; i < 8; ++i) kv[i] = Kc[(size_t)i * Dn + t];
    *(uint4*)(L + B_KT + t * 144) = make_uint4(pack2t(kv[0], kv[1]), pack2t(kv[2], kv[3]),
                                               pack2t(kv[4], kv[5]), pack2t(kv[6], kv[7]));
    *(uint4*)(L + B_KT + t * 144 + 16) = make_uint4(0, 0, 0, 0);
    *(uint4*)(L + B_KT + t * 144 + 32) = make_uint4(0, 0, 0, 0);
    *(uint4*)(L + B_KT + t * 144 + 48) = make_uint4(0, 0, 0, 0);
  } else if (t < 192) {
    int d = t - 128;
    float v2[8];
#pragma unroll
    for (int i = 0; i < 8; ++i) v2[i] = Vc[(size_t)i * Dn + h * 64 + d];
    *(uint4*)(L + B_VT + d * 144) = make_uint4(pack2t(v2[0], v2[1]), pack2t(v2[2], v2[3]),
                                               pack2t(v2[4], v2[5]), pack2t(v2[6], v2[7]));
    *(uint4*)(L + B_VT + d * 144 + 16) = make_uint4(0, 0, 0, 0);
    *(uint4*)(L + B_VT + d * 144 + 32) = make_uint4(0, 0, 0, 0);
    *(uint4*)(L + B_VT + d * 144 + 48) = make_uint4(0, 0, 0, 0);
  } else if (t < 256) {
    int d = t - 192;
    float v2[8], wc[8];
#pragma unroll
    for (int i = 0; i < 8; ++i) {
      v2[i] = Vc[(size_t)i * Dn + h * 64 + d];
      wc[i] = *(const float*)(L + B_WC + i * 4);
    }
    *(uint4*)(L + B_VTW + d * 144) =
        make_uint4(pack2t(wc[0] * v2[0], wc[1] * v2[1]), pack2t(wc[2] * v2[2], wc[3] * v2[3]),
                   pack2t(wc[4] * v2[4], wc[5] * v2[5]), pack2t(wc[6] * v2[6], wc[7] * v2[7]));
    *(uint4*)(L + B_VTW + d * 144 + 16) = make_uint4(0, 0, 0, 0);
    *(uint4*)(L + B_VTW + d * 144 + 32) = make_uint4(0, 0, 0, 0);
    *(uint4*)(L + B_VTW + d * 144 + 48) = make_uint4(0, 0, 0, 0);
  }
  __syncthreads();
  f32x4 outc = {0.f,0.f,0.f,0.f}, kbc = {0.f,0.f,0.f,0.f};
  f32x4 D00 = {0.f,0.f,0.f,0.f}, D01 = {0.f,0.f,0.f,0.f};
  f32x4 D10 = {0.f,0.f,0.f,0.f}, D11 = {0.f,0.f,0.f,0.f};
  {
    bf16x8 pA = *(const bf16x8*)(L + B_PCG + l16 * 80 + quad * 16);
    bf16x8 bK = *(const bf16x8*)(L + B_KT + (wv * 16 + l16) * 144 + quad * 16);
    kbc = MFMA16(pA, bK, kbc);
    if (wv < 4) {
      bf16x8 bV = *(const bf16x8*)(L + B_VT + (wv * 16 + l16) * 144 + quad * 16);
      outc = MFMA16(pA, bV, outc);
    }
    ckstep(0, D00, D01, D10, D11);
  }
  __syncthreads();
  if (wv < 4) {
#pragma unroll
    for (int r = 0; r < 4; ++r)
      *(unsigned short*)(L + B_VTW + (wv * 16 + l16) * 144 + (quad * 4 + r) * 2) = f2bf(-outc[r]);
  }
#pragma unroll
  for (int r = 0; r < 4; ++r)
    *(unsigned short*)(L + B_KT + (wv * 16 + l16) * 144 + (quad * 4 + r) * 2) = f2bf(kbc[r]);
  __syncthreads();
  ckstep(0, D00, D01, D10, D11);
#pragma unroll
  for (int r = 0; r < 4; ++r) {
    D00[r] = fminf(fmaxf(SCALE * D00[r], -CLIPV), CLIPV);
    D01[r] = fminf(fmaxf(SCALE * D01[r], -CLIPV), CLIPV);
    D10[r] = fminf(fmaxf(SCALE * D10[r], -CLIPV), CLIPV);
    D11[r] = fminf(fmaxf(SCALE * D11[r], -CLIPV), CLIPV);
  }

  // loss partials
  float dot = 0.f, nd2 = 0.f, nc2 = 0.f, cons = 0.f;
#pragma unroll
  for (int r = 0; r < 4; ++r) {
    dot += C00[r] * D00[r] + C01[r] * D01[r] + C10[r] * D10[r] + C11[r] * D11[r];
    nd2 += C00[r] * C00[r] + C01[r] * C01[r] + C10[r] * C10[r] + C11[r] * C11[r];
    nc2 += D00[r] * D00[r] + D01[r] * D01[r] + D10[r] * D10[r] + D11[r] * D11[r];
  }
  if (wv < 4) {
#pragma unroll
    for (int r = 0; r < 4; ++r) {
      float df = outacc[r] - outc[r];
      cons += df * df;
    }
  }
#pragma unroll
  for (int o = 32; o; o >>= 1) {
    dot += __shfl_xor(dot, o);
    nd2 += __shfl_xor(nd2, o);
    nc2 += __shfl_xor(nc2, o);
    cons += __shfl_xor(cons, o);
  }
  if (lane == 0) {
    float* red = (float*)(L + B_RED);
    red[wv * 4 + 0] = dot;
    red[wv * 4 + 1] = nd2;
    red[wv * 4 + 2] = nc2;
    red[wv * 4 + 3] = cons;
  }
  __syncthreads();
  if (t == 0) {
    const float* red = (const float*)(L + B_RED);
    float d_ = 0.f, n1 = 0.f, n2 = 0.f, cs = 0.f;
#pragma unroll
    for (int w = 0; w < 8; ++w) {
      d_ += red[w * 4 + 0];
      n1 += red[w * 4 + 1];
      n2 += red[w * 4 + 2];
      cs += red[w * 4 + 3];
    }
    atomicAdd(ws + PART_OFF_F + b * 4 + 0, d_);
    atomicAdd(ws + PART_OFF_F + b * 4 + 1, n1);
    atomicAdd(ws + PART_OFF_F + b * 4 + 2, n2);
    atomicAdd(ws + PART_OFF_F + b * 4 + 3, cs);
  }
}

__global__ void finalize_kernel(const float* __restrict__ ws, float* __restrict__ out) {
  __shared__ float sr[256];
  int i = threadIdx.x;
  const float* p = ws + PART_OFF_F + i * 4;
  float cosv = p[0] / (sqrtf(p[1]) * sqrtf(p[2]) + 1e-8f);
  sr[i] = (1.0f - cosv) + p[3] * (1.0f / (float)(Qn * Dn));
  __syncthreads();
  for (int off = 128; off; off >>= 1) {
    if (i < off) sr[i] += sr[i + off];
    __syncthreads();
  }
  if (i == 0) out[0] = sr[0] * (1.0f / (float)Bn);
}
}  // namespace

extern "C" void kernel_launch(void* const* d_in, const int* in_sizes, int n_in,
                              void* d_out, int out_size, void* d_ws, size_t ws_size,
                              hipStream_t stream) {
  const float* q = (const float*)d_in[0];
  const float* k = (const float*)d_in[1];
  const float* v = (const float*)d_in[2];
  const float* kc = (const float*)d_in[3];
  const float* vc = (const float*)d_in[4];
  float* out = (float*)d_out;
  float* ws = (float*)d_ws;
  scores_kernel<<<Bn, NT, 0, stream>>>(q, k, kc, ws);
  jac_kernel<<<2 * Bn, NT, 0, stream>>>(k, v, kc, vc, ws);
  finalize_kernel<<<1, 256, 0, stream>>>(ws, out);
}